// Round 3
// baseline (920.559 us; speedup 1.0000x reference)
//
#include <hip/hip_runtime.h>
#include <math.h>

// ---- problem constants ----
// D = 640; NET1=[640,512,64]; NET3=[640,640,512,64,512]
// W_TOTAL = 802816 ; B_TOTAL = 1728 ; x2 rows = 804544, each 64 wide
// weight row offsets: L1 wi=0, L2 wi=409600, L3 wi=737280, L4 wi=770048
// bias rows: L1 802816, L2 803456, L3 803968, L4 804032

// workspace layout (float offsets)
#define WS_H0    0      // 640
#define WS_H1N1  640    // 512
#define WS_H1N2  1152   // 512
#define WS_H2    1664   // 64   : "h" for W3
#define WS_INPT  1728   // 640
#define WS_X3A   2368   // 640
#define WS_X3B   3008   // 512
#define WS_CNT1  3584   // int: last-block counter for k1bc
#define WS_CNT2  3585   // int: last-block counter for gml2tail
#define WS_CNT3  3586   // int: last-block counter for bigT
#define WS_T     4096   // 804544 : t[r] = 0.5*tanh(w3[r]·h + b3[r])
#define WS_PART  808640 // 640*10 : per-chunk partials of generated layer 1

#define N_ROWS   804544
#define N_WAVES  12571   // N_ROWS / 64

typedef float vf4 __attribute__((ext_vector_type(4)));  // native vec for nontemporal builtins

__device__ __forceinline__ float leaky_f(float v) { return v >= 0.0f ? v : 0.01f * v; }

__device__ __forceinline__ float inpt_at(int i, const float* x, const float* po, const float* st) {
  return i < 64 ? x[i] : (i < 128 ? po[i - 64] : st[i - 128]);
}

// 0.5*tanh(d) = 0.5 - 1/(exp(2d)+1)
__device__ __forceinline__ float half_tanh(float d) {
  float t = exp2f(d * 2.8853900817779268f);  // exp(2d)
  return 0.5f - __builtin_amdgcn_rcpf(t + 1.0f);
}

// float4 dot of a row (IN floats) against LDS vector, wave-parallel
template <int IN>
__device__ __forceinline__ float row_dot(const float* __restrict__ wrow, const float* s_in, int lane) {
  const float4* w4 = (const float4*)wrow;
  const float4* s4 = (const float4*)s_in;
  float acc = 0.f;
  for (int j = lane; j < IN / 4; j += 64) {
    float4 a = w4[j];
    float4 b = s4[j];
    acc += a.x * b.x + a.y * b.y + a.z * b.z + a.w * b.w;
  }
  for (int off = 32; off; off >>= 1) acc += __shfl_xor(acc, off, 64);
  return acc;
}

// ---------- K1a: h0 = leaky(net2_w0@inpt+b0) [640], h1n1 = leaky(net1_w0@inpt+b0) [512]
// Also zeroes the three last-block counters (ws is poisoned each iteration).
__global__ __launch_bounds__(256) void k1a(const float* __restrict__ x, const float* __restrict__ po,
                                           const float* __restrict__ st,
                                           const float* __restrict__ w2_0, const float* __restrict__ b2_0,
                                           const float* __restrict__ w1_0, const float* __restrict__ b1_0,
                                           float* __restrict__ ws) {
  if (blockIdx.x == 0 && threadIdx.x < 3) ((int*)ws)[WS_CNT1 + threadIdx.x] = 0;
  __shared__ __align__(16) float s_in[640];
  for (int i = threadIdx.x; i < 640; i += 256) {
    float v = inpt_at(i, x, po, st);
    s_in[i] = v;
    ws[WS_INPT + i] = v;
  }
  __syncthreads();
  int wave = threadIdx.x >> 6, lane = threadIdx.x & 63;
  int o = blockIdx.x * 4 + wave;  // 0..1151
  const float* wrow;
  float bias;
  float* dst;
  if (o < 640) {
    wrow = w2_0 + (long long)o * 640; bias = b2_0[o]; dst = ws + WS_H0 + o;
  } else {
    int oo = o - 640;
    wrow = w1_0 + (long long)oo * 640; bias = b1_0[oo]; dst = ws + WS_H1N1 + oo;
  }
  float acc = row_dot<640>(wrow, s_in, lane);
  if (lane == 0) *dst = leaky_f(acc + bias);
}

// ---------- K1bc: h1n2 = leaky(net2_w1@h0+b1) [512] ; out = net1_w1@h1n1+b1 [64];
// last-finishing block computes h2 = leaky(net2_w2@h1n2+b2) [64] (fence+atomic,
// no dispatch-order assumption; continuation is 128 KB through one CU ~1.5 us).
__global__ __launch_bounds__(256) void k1bc(const float* __restrict__ w2_1, const float* __restrict__ b2_1,
                                            const float* __restrict__ w1_1, const float* __restrict__ b1_1,
                                            const float* __restrict__ w2_2, const float* __restrict__ b2_2,
                                            float* __restrict__ ws, float* __restrict__ out) {
  __shared__ __align__(16) float s_h0[640];
  __shared__ __align__(16) float s_h1[512];
  __shared__ int s_last;
  for (int i = threadIdx.x; i < 640; i += 256) s_h0[i] = ws[WS_H0 + i];
  for (int i = threadIdx.x; i < 512; i += 256) s_h1[i] = ws[WS_H1N1 + i];
  __syncthreads();
  int wave = threadIdx.x >> 6, lane = threadIdx.x & 63;
  int o = blockIdx.x * 4 + wave;  // 0..575
  if (o < 512) {
    float acc = row_dot<640>(w2_1 + (long long)o * 640, s_h0, lane);
    if (lane == 0) ws[WS_H1N2 + o] = leaky_f(acc + b2_1[o]);
  } else {
    int oo = o - 512;
    float acc = row_dot<512>(w1_1 + (long long)oo * 512, s_h1, lane);
    if (lane == 0) out[oo] = acc + b1_1[oo];
  }
  // ---- last-block continuation: h2 ----
  __syncthreads();
  __threadfence();  // release h1n2 writes device-wide before signaling
  if (threadIdx.x == 0) s_last = (atomicAdd((int*)ws + WS_CNT1, 1) == (int)gridDim.x - 1);
  __syncthreads();
  if (!s_last) return;
  __threadfence();  // acquire: observe all producers' h1n2 writes
  for (int i = threadIdx.x; i < 512; i += 256) s_h1[i] = ws[WS_H1N2 + i];
  __syncthreads();
#pragma unroll
  for (int r = 0; r < 16; r++) {
    int o2 = r * 4 + wave;  // 0..63
    float acc = row_dot<512>(w2_2 + (long long)o2 * 512, s_h1, lane);
    if (lane == 0) ws[WS_H2 + o2] = leaky_f(acc + b2_2[o2]);
  }
}

// ---------- bigT: t[r] = 0.5*tanh(w3[r,:]·h + b3[r]) for ALL 804544 rows,
// WITH generated-layer-1 fused in:
//  - nt loads on w3 (206 MB streamed once; keeps L2/L3 clean — round-1 A/B).
//  - coalesced epilogue: lane gl==q keeps row base+gl*4+g; one 256 B t-store/wave.
//  - the first 6400 waves (rows < 409600) each cover 64 consecutive elements of ONE
//    generated-L1 row (640 % 64 == 0): compute the 64-wide partial dot against inpt
//    in-register (full 64-lane butterfly) and write partials[o][chunk]. No atomics,
//    each slot written exactly once -> deterministic, fixed summation order.
//  - last-finishing block sums the 10 partials per row (+ generated bias) -> x3a.
__global__ __launch_bounds__(256) void bigT(const float* __restrict__ w3, const float* __restrict__ b3,
                                            float* __restrict__ ws) {
  float* t = ws + WS_T;
  __shared__ int s_last;
  int wid = blockIdx.x * 4 + (threadIdx.x >> 6);
  const bool active = wid < N_WAVES;
  if (!active) wid = 0;  // duplicate wave 0's work, suppress stores (all threads must reach barrier)
  const int lane = threadIdx.x & 63;
  const int g = lane >> 4;    // row-in-quad (0..3)
  const int gl = lane & 15;   // float4-slot within row
  float4 hv = ((const float4*)(ws + WS_H2))[gl];
  const long long base = (long long)wid * 64;
  const int myrow = (gl << 2) + g;           // row this lane owns for the epilogue
  float bmine = b3[base + myrow];            // coalesced (permuted within 256 B)
  const vf4* wp = (const vf4*)(w3 + (base << 6));  // 64 rows x 16 vec4
  vf4 v[16];
#pragma unroll
  for (int q = 0; q < 16; q++) v[q] = __builtin_nontemporal_load(&wp[((q * 4 + g) << 4) + gl]);
  float myd = 0.f;
#pragma unroll
  for (int q = 0; q < 16; q++) {
    float d = v[q].x * hv.x + v[q].y * hv.y + v[q].z * hv.z + v[q].w * hv.w;
    d += __shfl_xor(d, 1, 64);
    d += __shfl_xor(d, 2, 64);
    d += __shfl_xor(d, 4, 64);
    d += __shfl_xor(d, 8, 64);
    if (gl == q) myd = d;  // value identical to lane gl==0's: bit-identical result
  }
  float tval = half_tanh(myd + bmine);
  if (active) t[base + myrow] = tval;  // one coalesced 256 B store per wave
  // fused generated-L1 partial dot
  if (active && wid < 6400) {
    int o = wid / 10, chunk = wid - o * 10;  // row 640*o, elements [chunk*64, +64)
    float p = tval * ws[WS_INPT + chunk * 64 + myrow];
    p += __shfl_xor(p, 1, 64);
    p += __shfl_xor(p, 2, 64);
    p += __shfl_xor(p, 4, 64);
    p += __shfl_xor(p, 8, 64);
    p += __shfl_xor(p, 16, 64);
    p += __shfl_xor(p, 32, 64);
    if (lane == 0) ws[WS_PART + o * 10 + chunk] = p;
  }
  // ---- last-block continuation: finalize x3a ----
  __syncthreads();
  __threadfence();  // release t + partials
  if (threadIdx.x == 0) s_last = (atomicAdd((int*)ws + WS_CNT3, 1) == (int)gridDim.x - 1);
  __syncthreads();
  if (!s_last) return;
  __threadfence();  // acquire all producers' stores
  for (int o = threadIdx.x; o < 640; o += 256) {
    const float* pp = ws + WS_PART + o * 10;
    float s = 0.f;
#pragma unroll
    for (int c = 0; c < 10; c++) s += pp[c];  // fixed order: deterministic
    ws[WS_X3A + o] = leaky_f(s + t[802816 + o]);
  }
}

// ---------- gml2tail: generated layer 2 (512<-640) across 128 blocks x 256 threads
// (keeps L2-phase reads spread over 128 CUs); last-finishing block runs generated
// layers 3 (64<-512) and 4 (512<-64) — ~260 KB through one CU, ~4 us.
__global__ __launch_bounds__(256) void gml2tail(const float* __restrict__ t, float* __restrict__ ws,
                                                float* __restrict__ out) {
  __shared__ __align__(16) float s_in[640];  // phase 1: x3a ; tail: reused for x3b
  __shared__ __align__(16) float s_c[64];    // x3c
  __shared__ int s_last;
  const int tid = threadIdx.x;
  const int wave = tid >> 6, lane = tid & 63;
  for (int i = tid; i < 640; i += 256) s_in[i] = ws[WS_X3A + i];
  __syncthreads();
  // layer 2: one wave per output, exactly 512 = 128 blocks x 4 waves
  {
    int o = blockIdx.x * 4 + wave;  // 0..511
    float acc = row_dot<640>(t + 409600 + (long long)o * 640, s_in, lane);
    if (lane == 0) ws[WS_X3B + o] = leaky_f(acc + t[803456 + o]);
  }
  // ---- last-block continuation: layers 3 + 4 ----
  __syncthreads();
  __threadfence();
  if (tid == 0) s_last = (atomicAdd((int*)ws + WS_CNT2, 1) == (int)gridDim.x - 1);
  __syncthreads();
  if (!s_last) return;
  __threadfence();
  for (int i = tid; i < 512; i += 256) s_in[i] = ws[WS_X3B + i];
  __syncthreads();
  // layer 3: one wave per output, 16 rounds over 4 waves
#pragma unroll
  for (int r = 0; r < 16; r++) {
    int o3 = r * 4 + wave;  // 0..63
    float acc = row_dot<512>(t + 737280 + (long long)o3 * 512, s_in, lane);
    if (lane == 0) s_c[o3] = leaky_f(acc + t[803968 + o3]);
  }
  __syncthreads();
  // layer 4: 16-lane coop, 4 outputs/wave/round, 32 rounds; no activation
  const int g = lane >> 4, glx = lane & 15;
  float4 xc4 = ((const float4*)s_c)[glx];
#pragma unroll
  for (int r = 0; r < 32; r++) {
    int o4 = r * 16 + wave * 4 + g;  // 0..511
    const float4* row = (const float4*)(t + 770048 + (long long)o4 * 64);
    float4 wv = row[glx];
    float a = wv.x * xc4.x + wv.y * xc4.y + wv.z * xc4.z + wv.w * xc4.w;
    a += __shfl_xor(a, 1, 64);
    a += __shfl_xor(a, 2, 64);
    a += __shfl_xor(a, 4, 64);
    a += __shfl_xor(a, 8, 64);
    if (glx == 0) out[64 + o4] = a + t[804032 + o4];
  }
}

extern "C" void kernel_launch(void* const* d_in, const int* in_sizes, int n_in,
                              void* d_out, int out_size, void* d_ws, size_t ws_size,
                              hipStream_t stream) {
  const float* x    = (const float*)d_in[0];
  const float* po   = (const float*)d_in[1];
  const float* st   = (const float*)d_in[2];
  const float* w1_0 = (const float*)d_in[3];
  const float* b1_0 = (const float*)d_in[4];
  const float* w1_1 = (const float*)d_in[5];
  const float* b1_1 = (const float*)d_in[6];
  const float* w2_0 = (const float*)d_in[7];
  const float* b2_0 = (const float*)d_in[8];
  const float* w2_1 = (const float*)d_in[9];
  const float* b2_1 = (const float*)d_in[10];
  const float* w2_2 = (const float*)d_in[11];
  const float* b2_2 = (const float*)d_in[12];
  const float* w3   = (const float*)d_in[13];
  const float* b3   = (const float*)d_in[14];
  float* ws  = (float*)d_ws;
  float* out = (float*)d_out;
  float* t   = ws + WS_T;

  // 4 dispatches (was 7): k1c folded into k1bc, gml-L1 folded into bigT,
  // gmlTail folded into gml2tail. nt w3 stream untouched.
  k1a<<<288, 256, 0, stream>>>(x, po, st, w2_0, b2_0, w1_0, b1_0, ws);
  k1bc<<<144, 256, 0, stream>>>(w2_1, b2_1, w1_1, b1_1, w2_2, b2_2, ws, out);
  bigT<<<(N_WAVES + 3) / 4, 256, 0, stream>>>(w3, b3, ws);
  gml2tail<<<128, 256, 0, stream>>>(t, ws, out);
}

// Round 4
// 383.315 us; speedup vs baseline: 2.4016x; 2.4016x over previous
//
#include <hip/hip_runtime.h>
#include <math.h>

// ---- problem constants ----
// D = 640; NET1=[640,512,64]; NET3=[640,640,512,64,512]
// W_TOTAL = 802816 ; B_TOTAL = 1728 ; x2 rows = 804544, each 64 wide
// weight row offsets: L1 wi=0, L2 wi=409600, L3 wi=737280, L4 wi=770048
// bias rows: L1 802816, L2 803456, L3 803968, L4 804032

// workspace layout (float offsets)
#define WS_H0    0      // 640
#define WS_H1N1  640    // 512
#define WS_H1N2  1152   // 512
#define WS_H2    1664   // 64   : "h" for W3
#define WS_INPT  1728   // 640
#define WS_X3A   2368   // 640
#define WS_X3B   3008   // 512
#define WS_CNT1  3584   // int: last-block counter for k1bc
#define WS_CNT2  3585   // int: last-block counter for gml2tail
#define WS_T     4096   // 804544 : t[r] = 0.5*tanh(w3[r]·h + b3[r])

#define N_ROWS   804544
#define N_WAVES  12571   // N_ROWS / 64

typedef float vf4 __attribute__((ext_vector_type(4)));  // native vec for nontemporal builtins

__device__ __forceinline__ float leaky_f(float v) { return v >= 0.0f ? v : 0.01f * v; }

__device__ __forceinline__ float inpt_at(int i, const float* x, const float* po, const float* st) {
  return i < 64 ? x[i] : (i < 128 ? po[i - 64] : st[i - 128]);
}

// 0.5*tanh(d) = 0.5 - 1/(exp(2d)+1)
__device__ __forceinline__ float half_tanh(float d) {
  float t = exp2f(d * 2.8853900817779268f);  // exp(2d)
  return 0.5f - __builtin_amdgcn_rcpf(t + 1.0f);
}

// float4 dot of a row (IN floats) against LDS vector, wave-parallel
template <int IN>
__device__ __forceinline__ float row_dot(const float* __restrict__ wrow, const float* s_in, int lane) {
  const float4* w4 = (const float4*)wrow;
  const float4* s4 = (const float4*)s_in;
  float acc = 0.f;
  for (int j = lane; j < IN / 4; j += 64) {
    float4 a = w4[j];
    float4 b = s4[j];
    acc += a.x * b.x + a.y * b.y + a.z * b.z + a.w * b.w;
  }
  for (int off = 32; off; off >>= 1) acc += __shfl_xor(acc, off, 64);
  return acc;
}

// ---------- K1a: h0 = leaky(net2_w0@inpt+b0) [640], h1n1 = leaky(net1_w0@inpt+b0) [512]
// Also zeroes the two last-block counters (ws is poisoned each iteration).
__global__ __launch_bounds__(256) void k1a(const float* __restrict__ x, const float* __restrict__ po,
                                           const float* __restrict__ st,
                                           const float* __restrict__ w2_0, const float* __restrict__ b2_0,
                                           const float* __restrict__ w1_0, const float* __restrict__ b1_0,
                                           float* __restrict__ ws) {
  if (blockIdx.x == 0 && threadIdx.x < 2) ((int*)ws)[WS_CNT1 + threadIdx.x] = 0;
  __shared__ __align__(16) float s_in[640];
  for (int i = threadIdx.x; i < 640; i += 256) {
    float v = inpt_at(i, x, po, st);
    s_in[i] = v;
    ws[WS_INPT + i] = v;
  }
  __syncthreads();
  int wave = threadIdx.x >> 6, lane = threadIdx.x & 63;
  int o = blockIdx.x * 4 + wave;  // 0..1151
  const float* wrow;
  float bias;
  float* dst;
  if (o < 640) {
    wrow = w2_0 + (long long)o * 640; bias = b2_0[o]; dst = ws + WS_H0 + o;
  } else {
    int oo = o - 640;
    wrow = w1_0 + (long long)oo * 640; bias = b1_0[oo]; dst = ws + WS_H1N1 + oo;
  }
  float acc = row_dot<640>(wrow, s_in, lane);
  if (lane == 0) *dst = leaky_f(acc + bias);
}

// ---------- K1bc: h1n2 = leaky(net2_w1@h0+b1) [512] ; out = net1_w1@h1n1+b1 [64];
// last-finishing block computes h2 = leaky(net2_w2@h1n2+b2) [64] (fence+atomic,
// no dispatch-order assumption; continuation ~128 KB through one CU, ~1.5 us).
// NOTE: the last-block pattern is confined to SMALL kernels — round 3 showed that
// grafting it onto the MLP-critical bigT stream wrecks codegen (VGPR 32, 5x slower).
__global__ __launch_bounds__(256) void k1bc(const float* __restrict__ w2_1, const float* __restrict__ b2_1,
                                            const float* __restrict__ w1_1, const float* __restrict__ b1_1,
                                            const float* __restrict__ w2_2, const float* __restrict__ b2_2,
                                            float* __restrict__ ws, float* __restrict__ out) {
  __shared__ __align__(16) float s_h0[640];
  __shared__ __align__(16) float s_h1[512];
  __shared__ int s_last;
  for (int i = threadIdx.x; i < 640; i += 256) s_h0[i] = ws[WS_H0 + i];
  for (int i = threadIdx.x; i < 512; i += 256) s_h1[i] = ws[WS_H1N1 + i];
  __syncthreads();
  int wave = threadIdx.x >> 6, lane = threadIdx.x & 63;
  int o = blockIdx.x * 4 + wave;  // 0..575
  if (o < 512) {
    float acc = row_dot<640>(w2_1 + (long long)o * 640, s_h0, lane);
    if (lane == 0) ws[WS_H1N2 + o] = leaky_f(acc + b2_1[o]);
  } else {
    int oo = o - 512;
    float acc = row_dot<512>(w1_1 + (long long)oo * 512, s_h1, lane);
    if (lane == 0) out[oo] = acc + b1_1[oo];
  }
  // ---- last-block continuation: h2 ----
  __syncthreads();
  __threadfence();  // release h1n2 writes device-wide before signaling
  if (threadIdx.x == 0) s_last = (atomicAdd((int*)ws + WS_CNT1, 1) == (int)gridDim.x - 1);
  __syncthreads();
  if (!s_last) return;
  __threadfence();  // acquire: observe all producers' h1n2 writes
  for (int i = threadIdx.x; i < 512; i += 256) s_h1[i] = ws[WS_H1N2 + i];
  __syncthreads();
#pragma unroll
  for (int r = 0; r < 16; r++) {
    int o2 = r * 4 + wave;  // 0..63
    float acc = row_dot<512>(w2_2 + (long long)o2 * 512, s_h1, lane);
    if (lane == 0) ws[WS_H2 + o2] = leaky_f(acc + b2_2[o2]);
  }
}

// ---------- bigT: t[r] = 0.5*tanh(w3[r,:]·h + b3[r]) for ALL 804544 rows.
// EXACT round-2 form — do not touch: no barriers, no tail, early return, 16 nt
// float4 loads in flight (needs the full v[16] register budget for MLP; round-3's
// grafted tail collapsed it to VGPR=32 and 5x'd the runtime).
// Nontemporal loads on w3: 206 MB streamed exactly once; keeps L2/L3 clean.
// Coalesced epilogue: lane gl==q keeps row base+gl*4+g; one 256 B t-store and one
// wave-wide half_tanh per wave. Bit-identical reduction order.
__global__ __launch_bounds__(256) void bigT(const float* __restrict__ w3, const float* __restrict__ b3,
                                            const float* __restrict__ h2p, float* __restrict__ t) {
  int wid = blockIdx.x * 4 + (threadIdx.x >> 6);
  if (wid >= N_WAVES) return;  // no barriers below: early return safe
  const int lane = threadIdx.x & 63;
  const int g = lane >> 4;    // row-in-quad (0..3)
  const int gl = lane & 15;   // float4-slot within row
  float4 hv = ((const float4*)h2p)[gl];
  const long long base = (long long)wid * 64;
  const int myrow = (gl << 2) + g;           // row this lane owns for the epilogue
  float bmine = b3[base + myrow];            // coalesced (permuted within 256 B)
  const vf4* wp = (const vf4*)(w3 + (base << 6));  // 64 rows x 16 vec4
  vf4 v[16];
#pragma unroll
  for (int q = 0; q < 16; q++) v[q] = __builtin_nontemporal_load(&wp[((q * 4 + g) << 4) + gl]);
  float myd = 0.f;
#pragma unroll
  for (int q = 0; q < 16; q++) {
    float d = v[q].x * hv.x + v[q].y * hv.y + v[q].z * hv.z + v[q].w * hv.w;
    d += __shfl_xor(d, 1, 64);
    d += __shfl_xor(d, 2, 64);
    d += __shfl_xor(d, 4, 64);
    d += __shfl_xor(d, 8, 64);
    if (gl == q) myd = d;  // value identical to lane gl==0's: bit-identical result
  }
  t[base + myrow] = half_tanh(myd + bmine);  // one coalesced 256 B store per wave
}

// ---------- gml: generated layer from precomputed t.
// x3out[o] = act( dot(t[wi+o*IN .. ], x3in) + t[brow+o] ), wave per output.
template <int IN, bool LEAKY>
__global__ __launch_bounds__(256) void gml(const float* __restrict__ t, const float* __restrict__ x3in,
                                           float* __restrict__ x3out, long long wi, long long brow,
                                           int OUT) {
  __shared__ __align__(16) float s_in[IN];
  for (int i = threadIdx.x; i < IN; i += 256) s_in[i] = x3in[i];
  __syncthreads();
  int wave = threadIdx.x >> 6, lane = threadIdx.x & 63;
  int o = blockIdx.x * 4 + wave;
  if (o >= OUT) return;
  float acc = row_dot<IN>(t + wi + (long long)o * IN, s_in, lane);
  if (lane == 0) {
    acc += t[brow + o];  // generated bias
    x3out[o] = LEAKY ? leaky_f(acc) : acc;
  }
}

// ---------- gml2tail: generated layer 2 (512<-640) across 128 blocks x 256 threads
// (keeps L2-phase reads spread over 128 CUs); last-finishing block runs generated
// layers 3 (64<-512) and 4 (512<-64) — ~260 KB through one CU, ~4 us.
__global__ __launch_bounds__(256) void gml2tail(const float* __restrict__ t, float* __restrict__ ws,
                                                float* __restrict__ out) {
  __shared__ __align__(16) float s_in[640];  // phase 1: x3a ; tail: reused for x3b
  __shared__ __align__(16) float s_c[64];    // x3c
  __shared__ int s_last;
  const int tid = threadIdx.x;
  const int wave = tid >> 6, lane = tid & 63;
  for (int i = tid; i < 640; i += 256) s_in[i] = ws[WS_X3A + i];
  __syncthreads();
  // layer 2: one wave per output, exactly 512 = 128 blocks x 4 waves
  {
    int o = blockIdx.x * 4 + wave;  // 0..511
    float acc = row_dot<640>(t + 409600 + (long long)o * 640, s_in, lane);
    if (lane == 0) ws[WS_X3B + o] = leaky_f(acc + t[803456 + o]);
  }
  // ---- last-block continuation: layers 3 + 4 ----
  __syncthreads();
  __threadfence();
  if (tid == 0) s_last = (atomicAdd((int*)ws + WS_CNT2, 1) == (int)gridDim.x - 1);
  __syncthreads();
  if (!s_last) return;
  __threadfence();
  for (int i = tid; i < 512; i += 256) s_in[i] = ws[WS_X3B + i];
  __syncthreads();
  // layer 3: one wave per output, 16 rounds over 4 waves
#pragma unroll
  for (int r = 0; r < 16; r++) {
    int o3 = r * 4 + wave;  // 0..63
    float acc = row_dot<512>(t + 737280 + (long long)o3 * 512, s_in, lane);
    if (lane == 0) s_c[o3] = leaky_f(acc + t[803968 + o3]);
  }
  __syncthreads();
  // layer 4: 16-lane coop, 4 outputs/wave/round, 32 rounds; no activation
  const int g = lane >> 4, glx = lane & 15;
  float4 xc4 = ((const float4*)s_c)[glx];
#pragma unroll
  for (int r = 0; r < 32; r++) {
    int o4 = r * 16 + wave * 4 + g;  // 0..511
    const float4* row = (const float4*)(t + 770048 + (long long)o4 * 64);
    float4 wv = row[glx];
    float a = wv.x * xc4.x + wv.y * xc4.y + wv.z * xc4.z + wv.w * xc4.w;
    a += __shfl_xor(a, 1, 64);
    a += __shfl_xor(a, 2, 64);
    a += __shfl_xor(a, 4, 64);
    a += __shfl_xor(a, 8, 64);
    if (glx == 0) out[64 + o4] = a + t[804032 + o4];
  }
}

extern "C" void kernel_launch(void* const* d_in, const int* in_sizes, int n_in,
                              void* d_out, int out_size, void* d_ws, size_t ws_size,
                              hipStream_t stream) {
  const float* x    = (const float*)d_in[0];
  const float* po   = (const float*)d_in[1];
  const float* st   = (const float*)d_in[2];
  const float* w1_0 = (const float*)d_in[3];
  const float* b1_0 = (const float*)d_in[4];
  const float* w1_1 = (const float*)d_in[5];
  const float* b1_1 = (const float*)d_in[6];
  const float* w2_0 = (const float*)d_in[7];
  const float* b2_0 = (const float*)d_in[8];
  const float* w2_1 = (const float*)d_in[9];
  const float* b2_1 = (const float*)d_in[10];
  const float* w2_2 = (const float*)d_in[11];
  const float* b2_2 = (const float*)d_in[12];
  const float* w3   = (const float*)d_in[13];
  const float* b3   = (const float*)d_in[14];
  float* ws  = (float*)d_ws;
  float* out = (float*)d_out;
  float* t   = ws + WS_T;

  // 5 dispatches: bigT reverted to round-2 form (standalone, MLP-critical),
  // small-kernel fusions kept (k1c -> k1bc tail, gmlTail -> gml2tail tail).
  k1a<<<288, 256, 0, stream>>>(x, po, st, w2_0, b2_0, w1_0, b1_0, ws);
  k1bc<<<144, 256, 0, stream>>>(w2_1, b2_1, w1_1, b1_1, w2_2, b2_2, ws, out);
  bigT<<<(N_WAVES + 3) / 4, 256, 0, stream>>>(w3, b3, ws + WS_H2, t);
  gml<640, true><<<160, 256, 0, stream>>>(t, ws + WS_INPT, ws + WS_X3A, 0LL, 802816LL, 640);
  gml2tail<<<128, 256, 0, stream>>>(t, ws, out);
}

// Round 6
// 324.932 us; speedup vs baseline: 2.8331x; 1.1797x over previous
//
#include <hip/hip_runtime.h>
#include <math.h>

// ---- problem constants ----
// D = 640; NET1=[640,512,64]; NET3=[640,640,512,64,512]
// W_TOTAL = 802816 ; B_TOTAL = 1728 ; x2 rows = 804544, each 64 wide
// weight row offsets: L1 wi=0, L2 wi=409600, L3 wi=737280, L4 wi=770048
// bias rows: L1 802816, L2 803456, L3 803968, L4 804032

// workspace layout (float offsets)
#define WS_H0    0      // 640
#define WS_H1N1  640    // 512
#define WS_H1N2  1152   // 512
#define WS_H2    1664   // 64   : "h" for W3
#define WS_INPT  1728   // 640
#define WS_X3A   2368   // 640  (no longer materialized; kept for layout stability)
#define WS_X3B   3008   // 512
#define WS_T     4096   // 804544 : t[r] = 0.5*tanh(w3[r]·h + b3[r])
#define WS_PART  808640 // 640*10 : per-chunk partials of generated layer 1

#define N_ROWS   804544
#define N_WAVES  12571   // N_ROWS / 64

typedef float vf4 __attribute__((ext_vector_type(4)));  // native vec for nontemporal builtins

__device__ __forceinline__ float leaky_f(float v) { return v >= 0.0f ? v : 0.01f * v; }

__device__ __forceinline__ float inpt_at(int i, const float* x, const float* po, const float* st) {
  return i < 64 ? x[i] : (i < 128 ? po[i - 64] : st[i - 128]);
}

// 0.5*tanh(d) = 0.5 - 1/(exp(2d)+1)
__device__ __forceinline__ float half_tanh(float d) {
  float t = exp2f(d * 2.8853900817779268f);  // exp(2d)
  return 0.5f - __builtin_amdgcn_rcpf(t + 1.0f);
}

// float4 dot of a row (IN floats) against LDS vector, wave-parallel
template <int IN>
__device__ __forceinline__ float row_dot(const float* __restrict__ wrow, const float* s_in, int lane) {
  const float4* w4 = (const float4*)wrow;
  const float4* s4 = (const float4*)s_in;
  float acc = 0.f;
  for (int j = lane; j < IN / 4; j += 64) {
    float4 a = w4[j];
    float4 b = s4[j];
    acc += a.x * b.x + a.y * b.y + a.z * b.z + a.w * b.w;
  }
  for (int off = 32; off; off >>= 1) acc += __shfl_xor(acc, off, 64);
  return acc;
}

// ---------- K1a: h0 = leaky(net2_w0@inpt+b0) [640], h1n1 = leaky(net1_w0@inpt+b0) [512]
// (round-2 exact; no counters anywhere in this build — no fences, no atomics)
__global__ __launch_bounds__(256) void k1a(const float* __restrict__ x, const float* __restrict__ po,
                                           const float* __restrict__ st,
                                           const float* __restrict__ w2_0, const float* __restrict__ b2_0,
                                           const float* __restrict__ w1_0, const float* __restrict__ b1_0,
                                           float* __restrict__ ws) {
  __shared__ __align__(16) float s_in[640];
  for (int i = threadIdx.x; i < 640; i += 256) {
    float v = inpt_at(i, x, po, st);
    s_in[i] = v;
    ws[WS_INPT + i] = v;
  }
  __syncthreads();
  int wave = threadIdx.x >> 6, lane = threadIdx.x & 63;
  int o = blockIdx.x * 4 + wave;  // 0..1151
  const float* wrow;
  float bias;
  float* dst;
  if (o < 640) {
    wrow = w2_0 + (long long)o * 640; bias = b2_0[o]; dst = ws + WS_H0 + o;
  } else {
    int oo = o - 640;
    wrow = w1_0 + (long long)oo * 640; bias = b1_0[oo]; dst = ws + WS_H1N1 + oo;
  }
  float acc = row_dot<640>(wrow, s_in, lane);
  if (lane == 0) *dst = leaky_f(acc + bias);
}

// ---------- K1b: h1n2 = leaky(net2_w1@h0+b1) [512] ; out = net1_w1@h1n1+b1 [64]
// (round-2 exact. Stream-ordered kernel boundaries are the cheap fence on MI355X:
// rounds 1/4 showed per-block __threadfence last-block fusion costs ~55 us.)
__global__ __launch_bounds__(256) void k1b(const float* __restrict__ w2_1, const float* __restrict__ b2_1,
                                           const float* __restrict__ w1_1, const float* __restrict__ b1_1,
                                           float* __restrict__ ws, float* __restrict__ out) {
  __shared__ __align__(16) float s_h0[640];
  __shared__ __align__(16) float s_h1[512];
  for (int i = threadIdx.x; i < 640; i += 256) s_h0[i] = ws[WS_H0 + i];
  for (int i = threadIdx.x; i < 512; i += 256) s_h1[i] = ws[WS_H1N1 + i];
  __syncthreads();
  int wave = threadIdx.x >> 6, lane = threadIdx.x & 63;
  int o = blockIdx.x * 4 + wave;  // 0..575
  if (o < 512) {
    float acc = row_dot<640>(w2_1 + (long long)o * 640, s_h0, lane);
    if (lane == 0) ws[WS_H1N2 + o] = leaky_f(acc + b2_1[o]);
  } else {
    int oo = o - 512;
    float acc = row_dot<512>(w1_1 + (long long)oo * 512, s_h1, lane);
    if (lane == 0) out[oo] = acc + b1_1[oo];
  }
}

// ---------- K1c: h2 = leaky(net2_w2@h1n2+b2) [64]   (round-2 exact)
__global__ __launch_bounds__(256) void k1c(const float* __restrict__ w2_2, const float* __restrict__ b2_2,
                                           float* __restrict__ ws) {
  __shared__ __align__(16) float s_h[512];
  for (int i = threadIdx.x; i < 512; i += 256) s_h[i] = ws[WS_H1N2 + i];
  __syncthreads();
  int wave = threadIdx.x >> 6, lane = threadIdx.x & 63;
  int o = blockIdx.x * 4 + wave;  // 0..63
  float acc = row_dot<512>(w2_2 + (long long)o * 512, s_h, lane);
  if (lane == 0) ws[WS_H2 + o] = leaky_f(acc + b2_2[o]);
}

// ---------- bigT: t[r] = 0.5*tanh(w3[r,:]·h + b3[r]) for ALL 804544 rows.
// Load pipeline is round-2 exact — no barriers, no tail, early return, 16 nt float4
// loads in flight (round 3: grafting a barrier/tail collapsed VGPR to 32, spilled
// v[16] to scratch, 5x slower. Never again.)
// Round 5: waves with wid<6400 own 64 consecutive t-values of exactly ONE
// generated-L1 row (640%64==0); a 6-step butterfly + one scalar store emits
// partials[o][chunk] = sum_chunk t*inpt. Pure fast-path addition: ~8 VALU instrs +
// one 256 B L2-hit load + one 4 B store for half the waves; no sync of any kind.
// The L1 finish (sum of 10 partials + bias) moves into gml2x's prologue.
__global__ __launch_bounds__(256) void bigT(const float* __restrict__ w3, const float* __restrict__ b3,
                                            const float* __restrict__ h2p, float* __restrict__ t,
                                            const float* __restrict__ inpt, float* __restrict__ part) {
  int wid = blockIdx.x * 4 + (threadIdx.x >> 6);
  if (wid >= N_WAVES) return;  // no barriers below: early return safe
  const int lane = threadIdx.x & 63;
  const int g = lane >> 4;    // row-in-quad (0..3)
  const int gl = lane & 15;   // float4-slot within row
  float4 hv = ((const float4*)h2p)[gl];
  const long long base = (long long)wid * 64;
  const int myrow = (gl << 2) + g;           // row this lane owns for the epilogue
  float bmine = b3[base + myrow];            // coalesced (permuted within 256 B)
  const vf4* wp = (const vf4*)(w3 + (base << 6));  // 64 rows x 16 vec4
  vf4 v[16];
#pragma unroll
  for (int q = 0; q < 16; q++) v[q] = __builtin_nontemporal_load(&wp[((q * 4 + g) << 4) + gl]);
  float myd = 0.f;
#pragma unroll
  for (int q = 0; q < 16; q++) {
    float d = v[q].x * hv.x + v[q].y * hv.y + v[q].z * hv.z + v[q].w * hv.w;
    d += __shfl_xor(d, 1, 64);
    d += __shfl_xor(d, 2, 64);
    d += __shfl_xor(d, 4, 64);
    d += __shfl_xor(d, 8, 64);
    if (gl == q) myd = d;  // value identical to lane gl==0's: bit-identical result
  }
  float tval = half_tanh(myd + bmine);
  t[base + myrow] = tval;  // one coalesced 256 B store per wave
  // fused generated-L1 partial dot (first 6400 waves = rows < 409600 = L1 weights)
  if (wid < 6400) {
    int o = wid / 10, chunk = wid - o * 10;  // L1 row o, elements [chunk*64, +64)
    float p = tval * inpt[chunk * 64 + myrow];
    p += __shfl_xor(p, 1, 64);
    p += __shfl_xor(p, 2, 64);
    p += __shfl_xor(p, 4, 64);
    p += __shfl_xor(p, 8, 64);
    p += __shfl_xor(p, 16, 64);
    p += __shfl_xor(p, 32, 64);
    if (lane == 0) part[o * 10 + chunk] = p;  // each slot written exactly once
  }
}

// ---------- gml2x: generated layer 2 (512<-640). Prologue reconstructs x3a from
// the 10 bigT partials per row (fixed order -> deterministic; same summation as the
// round-3 correctness-validated path) + generated bias. 25.6 KB L2-broadcast across
// 128 blocks (~2 us) replaces the whole gml-L1 launch + its 1.64 MB t re-read.
__global__ __launch_bounds__(256) void gml2x(const float* __restrict__ t, const float* __restrict__ part,
                                             float* __restrict__ x3b) {
  __shared__ __align__(16) float s_in[640];  // x3a, reconstructed per block
  for (int o = threadIdx.x; o < 640; o += 256) {
    const float* pp = part + o * 10;
    float s = 0.f;
#pragma unroll
    for (int c = 0; c < 10; c++) s += pp[c];  // fixed order: deterministic
    s_in[o] = leaky_f(s + t[802816 + o]);
  }
  __syncthreads();
  int wave = threadIdx.x >> 6, lane = threadIdx.x & 63;
  int o = blockIdx.x * 4 + wave;  // 0..511 over 128 blocks
  float acc = row_dot<640>(t + 409600 + (long long)o * 640, s_in, lane);
  if (lane == 0) x3b[o] = leaky_f(acc + t[803456 + o]);
}

// ---------- gmlTail: generated layers 3 (64<-512) and 4 (512<-64) in ONE block.
// 1024 threads = 16 waves; __syncthreads between phases. (round-2 exact)
__global__ __launch_bounds__(1024) void gmlTail(const float* __restrict__ t, const float* __restrict__ ws,
                                                float* __restrict__ out) {
  __shared__ __align__(16) float s_b[512];  // x3b
  __shared__ __align__(16) float s_c[64];   // x3c
  const int tid = threadIdx.x;
  const int wave = tid >> 6, lane = tid & 63;  // wave 0..15
  for (int i = tid; i < 512; i += 1024) s_b[i] = ws[WS_X3B + i];
  __syncthreads();
  // layer 3: one wave per output, 4 rounds
#pragma unroll
  for (int r = 0; r < 4; r++) {
    int o = wave + r * 16;  // 0..63
    float acc = row_dot<512>(t + 737280 + (long long)o * 512, s_b, lane);
    if (lane == 0) s_c[o] = leaky_f(acc + t[803968 + o]);
  }
  __syncthreads();
  // layer 4: 16-lane coop, 4 outputs/wave/round, 8 rounds; no activation
  const int g = lane >> 4, gl = lane & 15;
  float4 xc4 = ((const float4*)s_c)[gl];
#pragma unroll
  for (int r = 0; r < 8; r++) {
    int o = r * 64 + wave * 4 + g;  // 0..511
    const float4* row = (const float4*)(t + 770048 + (long long)o * 64);
    float4 wv = row[gl];
    float a = wv.x * xc4.x + wv.y * xc4.y + wv.z * xc4.z + wv.w * xc4.w;
    a += __shfl_xor(a, 1, 64);
    a += __shfl_xor(a, 2, 64);
    a += __shfl_xor(a, 4, 64);
    a += __shfl_xor(a, 8, 64);
    if (gl == 0) out[64 + o] = a + t[804032 + o];
  }
}

extern "C" void kernel_launch(void* const* d_in, const int* in_sizes, int n_in,
                              void* d_out, int out_size, void* d_ws, size_t ws_size,
                              hipStream_t stream) {
  const float* x    = (const float*)d_in[0];
  const float* po   = (const float*)d_in[1];
  const float* st   = (const float*)d_in[2];
  const float* w1_0 = (const float*)d_in[3];
  const float* b1_0 = (const float*)d_in[4];
  const float* w1_1 = (const float*)d_in[5];
  const float* b1_1 = (const float*)d_in[6];
  const float* w2_0 = (const float*)d_in[7];
  const float* b2_0 = (const float*)d_in[8];
  const float* w2_1 = (const float*)d_in[9];
  const float* b2_1 = (const float*)d_in[10];
  const float* w2_2 = (const float*)d_in[11];
  const float* b2_2 = (const float*)d_in[12];
  const float* w3   = (const float*)d_in[13];
  const float* b3   = (const float*)d_in[14];
  float* ws  = (float*)d_ws;
  float* out = (float*)d_out;
  float* t   = ws + WS_T;

  // 6 dispatches; round-2 structure (no fences/atomics anywhere), gml-L1 launch
  // eliminated via bigT in-register partials + gml2x prologue reconstruction.
  k1a<<<288, 256, 0, stream>>>(x, po, st, w2_0, b2_0, w1_0, b1_0, ws);
  k1b<<<144, 256, 0, stream>>>(w2_1, b2_1, w1_1, b1_1, ws, out);
  k1c<<<16, 256, 0, stream>>>(w2_2, b2_2, ws);
  // the one heavy kernel: 206 MB streamed, fully parallel
  bigT<<<(N_WAVES + 3) / 4, 256, 0, stream>>>(w3, b3, ws + WS_H2, t, ws + WS_INPT, ws + WS_PART);
  // generated net
  gml2x<<<128, 256, 0, stream>>>(t, ws + WS_PART, ws + WS_X3B);
  gmlTail<<<1, 1024, 0, stream>>>(t, ws, out);
}